// Round 4
// baseline (745.919 us; speedup 1.0000x reference)
//
#include <hip/hip_runtime.h>
#include <hip/hip_bf16.h>

// B=128, C=20000, F=64, K=32.
// Outputs flat-concat: fa [B*C*64] | ca [B*C] | mean [B] | pred [B], all f32.

#define EPS_DENOM 1e-10f

typedef float floatx4 __attribute__((ext_vector_type(4)));

// ---------------------------------------------------------------------------
// Kernel A: case activations only (10 MB out). Numerics verbatim from the
// passing round-1 kernel: 16 lanes per case, per-group dot, shfl-xor tree.
// ---------------------------------------------------------------------------
__global__ __launch_bounds__(256) void ca_kernel(
    const float* __restrict__ q,
    const float* __restrict__ cases,
    const float* __restrict__ w_fa,
    const float* __restrict__ b_fa,
    const float* __restrict__ w_ca,
    const float* __restrict__ b_ca,
    float* __restrict__ ca_out,
    int B, int C)
{
    const int g = threadIdx.x & 15;   // feature group (features g*4 .. g*4+3)
    const int p = threadIdx.x >> 4;   // case slot 0..15
    const int c = blockIdx.x * 16 + p;
    const int b = blockIdx.y;
    if (c >= C) return;

    const int f4 = g * 4;
    const float4 qv = *reinterpret_cast<const float4*>(q     + (size_t)b * 64 + f4);
    const float4 cv = *reinterpret_cast<const float4*>(cases + (size_t)c * 64 + f4);
    const float4 wf = *reinterpret_cast<const float4*>(w_fa + f4);
    const float4 bf = *reinterpret_cast<const float4*>(b_fa + f4);
    const float4 wc = *reinterpret_cast<const float4*>(w_ca + f4);

    float d0 = qv.x - cv.x, d1 = qv.y - cv.y, d2 = qv.z - cv.z, d3 = qv.w - cv.w;
    float s0 = 1.0f / (1.0f + __expf(fmaf(d0 * d0, wf.x, -bf.x)));
    float s1 = 1.0f / (1.0f + __expf(fmaf(d1 * d1, wf.y, -bf.y)));
    float s2 = 1.0f / (1.0f + __expf(fmaf(d2 * d2, wf.z, -bf.z)));
    float s3 = 1.0f / (1.0f + __expf(fmaf(d3 * d3, wf.w, -bf.w)));

    float dot = s0 * wc.x + s1 * wc.y + s2 * wc.z + s3 * wc.w;
    dot += __shfl_xor(dot, 1, 64);
    dot += __shfl_xor(dot, 2, 64);
    dot += __shfl_xor(dot, 4, 64);
    dot += __shfl_xor(dot, 8, 64);

    if (g == 0) {
        float cav = 1.0f / (1.0f + __expf(-(dot + b_ca[0])));
        ca_out[(size_t)b * C + c] = cav;  // raw; topk rewrites in place
    }
}

// ---------------------------------------------------------------------------
// Kernel B: pure feature_activations streamer (655 MB out). No shuffles, no
// reduction; loads hoisted; nontemporal float4 stores.
// ---------------------------------------------------------------------------
__global__ __launch_bounds__(256) void fa_kernel(
    const float* __restrict__ q,
    const float* __restrict__ cases,
    const float* __restrict__ w_fa,
    const float* __restrict__ b_fa,
    float* __restrict__ fa_out,
    int B, int C)
{
    const int g  = threadIdx.x & 15;
    const int p  = threadIdx.x >> 4;
    const int b  = blockIdx.y;
    const int c0 = blockIdx.x * 64 + p;
    const int f4 = g * 4;

    const float4 qv = *reinterpret_cast<const float4*>(q    + (size_t)b * 64 + f4);
    const float4 wf = *reinterpret_cast<const float4*>(w_fa + f4);
    const float4 bf = *reinterpret_cast<const float4*>(b_fa + f4);

    float4 cv[4];
    #pragma unroll
    for (int j = 0; j < 4; ++j) {
        int c = c0 + j * 16;
        if (c > C - 1) c = C - 1;  // clamp: load stays valid, store is guarded
        cv[j] = *reinterpret_cast<const float4*>(cases + (size_t)c * 64 + f4);
    }

    #pragma unroll
    for (int j = 0; j < 4; ++j) {
        const int c = c0 + j * 16;
        if (c < C) {
            float d0 = qv.x - cv[j].x, d1 = qv.y - cv[j].y;
            float d2 = qv.z - cv[j].z, d3 = qv.w - cv[j].w;
            float s0 = 1.0f / (1.0f + __expf(fmaf(d0 * d0, wf.x, -bf.x)));
            float s1 = 1.0f / (1.0f + __expf(fmaf(d1 * d1, wf.y, -bf.y)));
            float s2 = 1.0f / (1.0f + __expf(fmaf(d2 * d2, wf.z, -bf.z)));
            float s3 = 1.0f / (1.0f + __expf(fmaf(d3 * d3, wf.w, -bf.w)));
            floatx4 sv = { s0, s1, s2, s3 };
            __builtin_nontemporal_store(
                sv, reinterpret_cast<floatx4*>(fa_out + ((size_t)b * C + c) * 64 + f4));
        }
    }
}

// ---------------------------------------------------------------------------
// Kernel C: per-row exact top-K via radix select with wave-aggregated
// histogram (sigmoid values cluster into few bins -> LDS atomics serialize
// 64-way without aggregation). One block per query row.
// ---------------------------------------------------------------------------
#define TPB2 256

__global__ __launch_bounds__(TPB2) void topk_kernel(
    float* __restrict__ ca,
    const float* __restrict__ labels,
    float* __restrict__ out_mean,
    float* __restrict__ out_pred,
    int C, const int* __restrict__ kp)
{
    __shared__ unsigned int hist[256];
    __shared__ unsigned int s_bsel;
    __shared__ int s_cum;
    __shared__ float s_red[TPB2];
    __shared__ float s_red2[TPB2];
    __shared__ int eq_buf[1024];
    __shared__ int eq_cnt;
    __shared__ int sel_eq[256];
    __shared__ int s_nsel;

    const int b = blockIdx.x;
    const int t = threadIdx.x;
    const int lane = t & 63;
    float* row = ca + (size_t)b * C;

    int K = *kp;
    if (K < 1) K = 1;
    if (K > 256) K = 256;

    const int Cpad = ((C + TPB2 - 1) / TPB2) * TPB2;

    // ---- radix select: exact K-th largest value (as uint key) ----
    unsigned int prefix = 0, pmask = 0;
    int remaining = K;

    for (int pass = 0; pass < 4; ++pass) {
        const int shift = 24 - 8 * pass;
        hist[t] = 0;
        __syncthreads();
        for (int i0 = 0; i0 < Cpad; i0 += TPB2) {
            const int i = i0 + t;
            unsigned int key = (i < C) ? __float_as_uint(row[i]) : 0u;
            bool valid = (i < C) && ((key & pmask) == prefix);
            int d = (int)((key >> shift) & 255u);
            // wave-aggregated histogram update
            unsigned long long m = __ballot(valid);
            while (m) {
                int leader = __ffsll(m) - 1;
                int dl = __shfl(d, leader, 64);
                unsigned long long match = __ballot(valid && (d == dl));
                if (lane == leader)
                    atomicAdd(&hist[dl], (unsigned)__popcll(match));
                m &= ~match;
            }
        }
        __syncthreads();
        if (t == 0) {
            int cum = 0;
            int bsel = 0;
            for (int bin = 255; bin >= 0; --bin) {
                int h = (int)hist[bin];
                if (cum + h >= remaining) { bsel = bin; break; }
                cum += h;
            }
            s_bsel = (unsigned)bsel;
            s_cum = cum;
        }
        __syncthreads();
        prefix |= s_bsel << shift;
        pmask  |= 255u << shift;
        remaining -= s_cum;
        __syncthreads();
    }

    const float v32f = __uint_as_float(prefix);  // exact K-th largest value
    const int n_take = remaining;                // # ties (== v32f) to keep, >= 1

    // ---- Pass A: sum of strictly-greater values; collect tie indices ----
    if (t == 0) eq_cnt = 0;
    __syncthreads();
    float sum_gt = 0.0f;
    for (int i = t; i < C; i += TPB2) {
        float v = row[i];
        if (v > v32f) {
            sum_gt += v;
        } else if (v == v32f) {
            int slot = atomicAdd(&eq_cnt, 1);
            if (slot < 1024) eq_buf[slot] = i;
        }
    }
    s_red[t] = sum_gt;
    __syncthreads();
    for (int off = 128; off > 0; off >>= 1) {
        if (t < off) s_red[t] += s_red[t + off];
        __syncthreads();
    }
    const float denom_gt = s_red[0];
    const int n_eq = eq_cnt;

    // ---- choose which ties to keep (lowest indices win, as in lax.top_k) ----
    if (n_eq <= n_take) {
        if (t < n_eq) sel_eq[t] = eq_buf[t];
        if (t == 0) s_nsel = n_eq;
    } else if (n_eq <= 1024) {
        for (int e = t; e < n_eq; e += TPB2) {
            int idx = eq_buf[e];
            int rank = 0;
            for (int j = 0; j < n_eq; ++j) rank += (eq_buf[j] < idx) ? 1 : 0;
            if (rank < n_take) sel_eq[rank] = idx;
        }
        if (t == 0) s_nsel = n_take;
    } else {
        if (t == 0) {  // pathological tie flood: serial fallback
            int cnt = 0;
            for (int i = 0; i < C && cnt < n_take; ++i)
                if (row[i] == v32f) sel_eq[cnt++] = i;
            s_nsel = cnt;
        }
    }
    __syncthreads();
    const int nsel = s_nsel;
    const float denom = denom_gt + (float)nsel * v32f + EPS_DENOM;

    // ---- Pass B: rewrite row in place; accumulate label sums ----
    float lsum = 0.0f, psum = 0.0f;
    for (int i = t; i < C; i += TPB2) {
        float v = row[i];
        float outv = 0.0f;
        bool sel = (v > v32f);
        if (!sel && v == v32f) {
            for (int e = 0; e < nsel; ++e)
                if (sel_eq[e] == i) { sel = true; break; }
        }
        if (sel) {
            outv = v / denom;
            float lab = labels[i];
            lsum += lab;
            psum += outv * lab;
        }
        row[i] = outv;
    }
    s_red[t] = lsum;
    s_red2[t] = psum;
    __syncthreads();
    for (int off = 128; off > 0; off >>= 1) {
        if (t < off) { s_red[t] += s_red[t + off]; s_red2[t] += s_red2[t + off]; }
        __syncthreads();
    }
    if (t == 0) {
        out_mean[b] = s_red[0] / (float)K;
        out_pred[b] = s_red2[0];
    }
}

extern "C" void kernel_launch(void* const* d_in, const int* in_sizes, int n_in,
                              void* d_out, int out_size, void* d_ws, size_t ws_size,
                              hipStream_t stream) {
    const float* q      = (const float*)d_in[0];
    const float* cases  = (const float*)d_in[1];
    const float* labels = (const float*)d_in[2];
    const float* w_fa   = (const float*)d_in[3];
    const float* b_fa   = (const float*)d_in[4];
    const float* w_ca   = (const float*)d_in[5];
    const float* b_ca   = (const float*)d_in[6];
    const int*   kp     = (const int*)d_in[7];

    const int F = in_sizes[3];          // 64
    const int B = in_sizes[0] / F;      // 128
    const int C = in_sizes[1] / F;      // 20000

    float* out      = (float*)d_out;
    const size_t FA = (size_t)B * C * F;
    float* fa_out   = out;
    float* ca_out   = out + FA;
    float* out_mean = ca_out + (size_t)B * C;
    float* out_pred = out_mean + B;

    dim3 gA((C + 15) / 16, B);
    ca_kernel<<<gA, 256, 0, stream>>>(q, cases, w_fa, b_fa, w_ca, b_ca,
                                      ca_out, B, C);
    topk_kernel<<<B, TPB2, 0, stream>>>(ca_out, labels, out_mean, out_pred, C, kp);

    dim3 gB((C + 63) / 64, B);
    fa_kernel<<<gB, 256, 0, stream>>>(q, cases, w_fa, b_fa, fa_out, B, C);
}

// Round 5
// 427.131 us; speedup vs baseline: 1.7463x; 1.7463x over previous
//
#include <hip/hip_runtime.h>
#include <hip/hip_bf16.h>

// B=128, C=20000, F=64, K=32.
// Outputs flat-concat: fa [B*C*64] | ca [B*C] | mean [B] | pred [B], all f32.

#define EPS_DENOM 1e-10f

typedef float floatx4 __attribute__((ext_vector_type(4)));

// ---------------------------------------------------------------------------
// Kernel A: case activations only (10 MB out). Numerics verbatim from the
// passing round-1 kernel: 16 lanes per case, per-group dot, shfl-xor tree.
// ---------------------------------------------------------------------------
__global__ __launch_bounds__(256) void ca_kernel(
    const float* __restrict__ q,
    const float* __restrict__ cases,
    const float* __restrict__ w_fa,
    const float* __restrict__ b_fa,
    const float* __restrict__ w_ca,
    const float* __restrict__ b_ca,
    float* __restrict__ ca_out,
    int B, int C)
{
    const int g = threadIdx.x & 15;   // feature group (features g*4 .. g*4+3)
    const int p = threadIdx.x >> 4;   // case slot 0..15
    const int c = blockIdx.x * 16 + p;
    const int b = blockIdx.y;
    if (c >= C) return;

    const int f4 = g * 4;
    const float4 qv = *reinterpret_cast<const float4*>(q     + (size_t)b * 64 + f4);
    const float4 cv = *reinterpret_cast<const float4*>(cases + (size_t)c * 64 + f4);
    const float4 wf = *reinterpret_cast<const float4*>(w_fa + f4);
    const float4 bf = *reinterpret_cast<const float4*>(b_fa + f4);
    const float4 wc = *reinterpret_cast<const float4*>(w_ca + f4);

    float d0 = qv.x - cv.x, d1 = qv.y - cv.y, d2 = qv.z - cv.z, d3 = qv.w - cv.w;
    float s0 = 1.0f / (1.0f + __expf(fmaf(d0 * d0, wf.x, -bf.x)));
    float s1 = 1.0f / (1.0f + __expf(fmaf(d1 * d1, wf.y, -bf.y)));
    float s2 = 1.0f / (1.0f + __expf(fmaf(d2 * d2, wf.z, -bf.z)));
    float s3 = 1.0f / (1.0f + __expf(fmaf(d3 * d3, wf.w, -bf.w)));

    float dot = s0 * wc.x + s1 * wc.y + s2 * wc.z + s3 * wc.w;
    dot += __shfl_xor(dot, 1, 64);
    dot += __shfl_xor(dot, 2, 64);
    dot += __shfl_xor(dot, 4, 64);
    dot += __shfl_xor(dot, 8, 64);

    if (g == 0) {
        float cav = 1.0f / (1.0f + __expf(-(dot + b_ca[0])));
        ca_out[(size_t)b * C + c] = cav;  // raw; topk rewrites in place
    }
}

// ---------------------------------------------------------------------------
// Kernel B: feature_activations streamer. Each block owns 64 cases (cached in
// registers), loops over a chunk of queries. Template A/B: NT vs plain store.
// ---------------------------------------------------------------------------
template <bool NT>
__global__ __launch_bounds__(256) void fa_stream_kernel(
    const float* __restrict__ q,
    const float* __restrict__ cases,
    const float* __restrict__ w_fa,
    const float* __restrict__ b_fa,
    float* __restrict__ fa_out,
    int C, int bchunk, int b_base, int b_end)
{
    const int g  = threadIdx.x & 15;
    const int p  = threadIdx.x >> 4;
    const int c0 = blockIdx.x * 64 + p;
    const int f4 = g * 4;

    const float4 wf = *reinterpret_cast<const float4*>(w_fa + f4);
    const float4 bf = *reinterpret_cast<const float4*>(b_fa + f4);

    float4 cv[4];
    #pragma unroll
    for (int j = 0; j < 4; ++j) {
        int c = c0 + j * 16;
        if (c > C - 1) c = C - 1;  // clamp load; store guarded below
        cv[j] = *reinterpret_cast<const float4*>(cases + (size_t)c * 64 + f4);
    }

    int b0 = b_base + blockIdx.y * bchunk;
    int b1 = b0 + bchunk;
    if (b1 > b_end) b1 = b_end;

    for (int b = b0; b < b1; ++b) {
        const float4 qv = *reinterpret_cast<const float4*>(q + (size_t)b * 64 + f4);
        #pragma unroll
        for (int j = 0; j < 4; ++j) {
            const int c = c0 + j * 16;
            if (c < C) {
                float d0 = qv.x - cv[j].x, d1 = qv.y - cv[j].y;
                float d2 = qv.z - cv[j].z, d3 = qv.w - cv[j].w;
                float s0 = 1.0f / (1.0f + __expf(fmaf(d0 * d0, wf.x, -bf.x)));
                float s1 = 1.0f / (1.0f + __expf(fmaf(d1 * d1, wf.y, -bf.y)));
                float s2 = 1.0f / (1.0f + __expf(fmaf(d2 * d2, wf.z, -bf.z)));
                float s3 = 1.0f / (1.0f + __expf(fmaf(d3 * d3, wf.w, -bf.w)));
                floatx4 sv = { s0, s1, s2, s3 };
                floatx4* dst = reinterpret_cast<floatx4*>(
                    fa_out + ((size_t)b * C + c) * 64 + f4);
                if (NT) __builtin_nontemporal_store(sv, dst);
                else    *dst = sv;
            }
        }
    }
}

// ---------------------------------------------------------------------------
// Kernel C: per-row exact top-K via radix select (plain LDS-atomic histogram
// — wave-aggregation measured 15x WORSE in round 4), then normalize in place
// + scalar outputs. One block per query row.
// ---------------------------------------------------------------------------
#define TPB2 256

__global__ __launch_bounds__(TPB2) void topk_kernel(
    float* __restrict__ ca,
    const float* __restrict__ labels,
    float* __restrict__ out_mean,
    float* __restrict__ out_pred,
    int C, const int* __restrict__ kp)
{
    __shared__ unsigned int hist[256];
    __shared__ unsigned int s_bsel;
    __shared__ int s_cum;
    __shared__ float s_red[TPB2];
    __shared__ float s_red2[TPB2];
    __shared__ int eq_buf[1024];
    __shared__ int eq_cnt;
    __shared__ int sel_eq[256];
    __shared__ int s_nsel;

    const int b = blockIdx.x;
    const int t = threadIdx.x;
    float* row = ca + (size_t)b * C;

    int K = *kp;
    if (K < 1) K = 1;
    if (K > 256) K = 256;

    // ---- radix select: exact K-th largest value (as uint key) ----
    unsigned int prefix = 0, pmask = 0;
    int remaining = K;

    for (int pass = 0; pass < 4; ++pass) {
        const int shift = 24 - 8 * pass;
        hist[t] = 0;
        __syncthreads();
        for (int i = t; i < C; i += TPB2) {
            unsigned int k = __float_as_uint(row[i]);
            if ((k & pmask) == prefix)
                atomicAdd(&hist[(k >> shift) & 255u], 1u);
        }
        __syncthreads();
        if (t == 0) {
            int cum = 0;
            int bsel = 0;
            for (int bin = 255; bin >= 0; --bin) {
                int h = (int)hist[bin];
                if (cum + h >= remaining) { bsel = bin; break; }
                cum += h;
            }
            s_bsel = (unsigned)bsel;
            s_cum = cum;
        }
        __syncthreads();
        prefix |= s_bsel << shift;
        pmask  |= 255u << shift;
        remaining -= s_cum;
        __syncthreads();
    }

    const float v32f = __uint_as_float(prefix);  // exact K-th largest value
    const int n_take = remaining;                // # ties (== v32f) to keep, >= 1

    // ---- Pass A: sum of strictly-greater values; collect tie indices ----
    if (t == 0) eq_cnt = 0;
    __syncthreads();
    float sum_gt = 0.0f;
    for (int i = t; i < C; i += TPB2) {
        float v = row[i];
        if (v > v32f) {
            sum_gt += v;
        } else if (v == v32f) {
            int slot = atomicAdd(&eq_cnt, 1);
            if (slot < 1024) eq_buf[slot] = i;
        }
    }
    s_red[t] = sum_gt;
    __syncthreads();
    for (int off = 128; off > 0; off >>= 1) {
        if (t < off) s_red[t] += s_red[t + off];
        __syncthreads();
    }
    const float denom_gt = s_red[0];
    const int n_eq = eq_cnt;

    // ---- choose which ties to keep (lowest indices win, as in lax.top_k) ----
    if (n_eq <= n_take) {
        if (t < n_eq) sel_eq[t] = eq_buf[t];
        if (t == 0) s_nsel = n_eq;
    } else if (n_eq <= 1024) {
        for (int e = t; e < n_eq; e += TPB2) {
            int idx = eq_buf[e];
            int rank = 0;
            for (int j = 0; j < n_eq; ++j) rank += (eq_buf[j] < idx) ? 1 : 0;
            if (rank < n_take) sel_eq[rank] = idx;
        }
        if (t == 0) s_nsel = n_take;
    } else {
        if (t == 0) {  // pathological tie flood: serial fallback
            int cnt = 0;
            for (int i = 0; i < C && cnt < n_take; ++i)
                if (row[i] == v32f) sel_eq[cnt++] = i;
            s_nsel = cnt;
        }
    }
    __syncthreads();
    const int nsel = s_nsel;
    const float denom = denom_gt + (float)nsel * v32f + EPS_DENOM;

    // ---- Pass B: rewrite row in place; accumulate label sums ----
    float lsum = 0.0f, psum = 0.0f;
    for (int i = t; i < C; i += TPB2) {
        float v = row[i];
        float outv = 0.0f;
        bool sel = (v > v32f);
        if (!sel && v == v32f) {
            for (int e = 0; e < nsel; ++e)
                if (sel_eq[e] == i) { sel = true; break; }
        }
        if (sel) {
            outv = v / denom;
            float lab = labels[i];
            lsum += lab;
            psum += outv * lab;
        }
        row[i] = outv;
    }
    s_red[t] = lsum;
    s_red2[t] = psum;
    __syncthreads();
    for (int off = 128; off > 0; off >>= 1) {
        if (t < off) { s_red[t] += s_red[t + off]; s_red2[t] += s_red2[t + off]; }
        __syncthreads();
    }
    if (t == 0) {
        out_mean[b] = s_red[0] / (float)K;
        out_pred[b] = s_red2[0];
    }
}

extern "C" void kernel_launch(void* const* d_in, const int* in_sizes, int n_in,
                              void* d_out, int out_size, void* d_ws, size_t ws_size,
                              hipStream_t stream) {
    const float* q      = (const float*)d_in[0];
    const float* cases  = (const float*)d_in[1];
    const float* labels = (const float*)d_in[2];
    const float* w_fa   = (const float*)d_in[3];
    const float* b_fa   = (const float*)d_in[4];
    const float* w_ca   = (const float*)d_in[5];
    const float* b_ca   = (const float*)d_in[6];
    const int*   kp     = (const int*)d_in[7];

    const int F = in_sizes[3];          // 64
    const int B = in_sizes[0] / F;      // 128
    const int C = in_sizes[1] / F;      // 20000

    float* out      = (float*)d_out;
    const size_t FA = (size_t)B * C * F;
    float* fa_out   = out;
    float* ca_out   = out + FA;
    float* out_mean = ca_out + (size_t)B * C;
    float* out_pred = out_mean + B;

    dim3 gA((C + 15) / 16, B);
    ca_kernel<<<gA, 256, 0, stream>>>(q, cases, w_fa, b_fa, w_ca, b_ca,
                                      ca_out, B, C);
    topk_kernel<<<B, TPB2, 0, stream>>>(ca_out, labels, out_mean, out_pred, C, kp);

    // fa split: first half NT stores, second half regular stores (A/B probe).
    const int cblocks = (C + 63) / 64;
    const int half = B / 2;                 // 64
    const int ychunks = 4;
    const int bchunk = (half + ychunks - 1) / ychunks;  // 16
    dim3 gB(cblocks, ychunks);
    fa_stream_kernel<true><<<gB, 256, 0, stream>>>(
        q, cases, w_fa, b_fa, fa_out, C, bchunk, 0, half);
    fa_stream_kernel<false><<<gB, 256, 0, stream>>>(
        q, cases, w_fa, b_fa, fa_out, C, bchunk, half, B);
}